// Round 3
// baseline (111.618 us; speedup 1.0000x reference)
//
#include <hip/hip_runtime.h>
#include <math.h>

#define N_INW     1024
#define N_DEPTH   8
#define N_GROW    512
#define N_BATCH   4096
#define N_THREADS 256    // 4 independent waves/WG; 1 batch-column per wave
#define N_LAYERS  64
#define SLAB_B    9792   // fp16 slab: 4608 rows * 2 B + (r>>5)*4 pad

typedef __attribute__((ext_vector_type(2))) float    F2;
typedef __attribute__((ext_vector_type(2))) _Float16 h2;

// fp16 slab (per wave): row r -> half at byte (r<<1) + ((r>>5)<<2).
// Pad is a multiple of 4 so even-row pairs are dword-aligned.
#define ADDR(r) (((r) << 1) + (((r) >> 5) << 2))

// ---- setup: fp16 cs table + precomputed u16 LDS byte-offsets ----
// layer g, lane blk: 8 cos halves at byte g*2048 + blk*32, 8 sin halves at +16.
__global__ void precompute_kernel(const float* __restrict__ angles,
                                  const int*   __restrict__ indices,
                                  _Float16* __restrict__ csh,
                                  unsigned short* __restrict__ addrs) {
    int i = blockIdx.x * blockDim.x + threadIdx.x;
    if (i < N_LAYERS * 512) {
        int g = i >> 9, p = i & 511, blk = p >> 3, j = p & 7;
        float a = angles[i];
        _Float16* base = csh + g * 1024 + blk * 16;   // halves
        base[j]     = (_Float16)cosf(a);
        base[8 + j] = (_Float16)sinf(a);
    }
    if (i < N_DEPTH * N_INW) {
        int v = indices[i];
        addrs[i] = (unsigned short)ADDR(v);
    }
}

#define PKU(x, y) __builtin_bit_cast(unsigned int,                             \
                      __builtin_amdgcn_cvt_pkrtz((x), (y)))

#define FENCE() __builtin_amdgcn_sched_barrier(0)

// ---- rotations ----
// Register r holds values (2r, 2r+1) of ONE column in (lo, hi) halves.

// stride-1: rotate WITHIN a register. cs half selected by op_sel (L=lo, H=hi):
//   t  = (s*b, s*a)           via src1 half-swap
//   x' = (c*a + s*b, c*b - s*a) via neg_hi on src2
#define ROT1_L(X, CW, SW) do { unsigned _t;                                    \
    asm("v_pk_mul_f16 %1, %3, %0 op_sel:[0,1] op_sel_hi:[0,0]\n\t"             \
        "v_pk_fma_f16 %0, %2, %0, %1 op_sel:[0,0,0] op_sel_hi:[0,1,1] "        \
            "neg_hi:[0,0,1]"                                                   \
        : "+v"(X), "=&v"(_t) : "v"(CW), "v"(SW)); } while (0)
#define ROT1_H(X, CW, SW) do { unsigned _t;                                    \
    asm("v_pk_mul_f16 %1, %3, %0 op_sel:[1,1] op_sel_hi:[1,0]\n\t"             \
        "v_pk_fma_f16 %0, %2, %0, %1 op_sel:[1,0,0] op_sel_hi:[1,1,1] "        \
            "neg_hi:[0,0,1]"                                                   \
        : "+v"(X), "=&v"(_t) : "v"(CW), "v"(SW)); } while (0)

// strides 2/4/8: elementwise packed rotation between two registers.
#define ROTPH(LO, HI, CW, SW) do {                                             \
    h2 _c = __builtin_bit_cast(h2, (unsigned)(CW));                            \
    h2 _s = __builtin_bit_cast(h2, (unsigned)(SW));                            \
    h2 _l = LO, _h = HI;                                                       \
    LO = _c * _l + _s * _h; HI = _c * _h - _s * _l; } while (0)

// full 4-layer half-module (strides 1,2,4,8) on x0..x7
#define ROT4(C0,S0,C1,S1,C2,S2,C3,S3) do {                                     \
    ROT1_L(x0,C0.x,S0.x); ROT1_H(x1,C0.x,S0.x);                                \
    ROT1_L(x2,C0.y,S0.y); ROT1_H(x3,C0.y,S0.y);                                \
    ROT1_L(x4,C0.z,S0.z); ROT1_H(x5,C0.z,S0.z);                                \
    ROT1_L(x6,C0.w,S0.w); ROT1_H(x7,C0.w,S0.w);                                \
    ROTPH(x0,x1,C1.x,S1.x); ROTPH(x2,x3,C1.y,S1.y);                            \
    ROTPH(x4,x5,C1.z,S1.z); ROTPH(x6,x7,C1.w,S1.w);                            \
    ROTPH(x0,x2,C2.x,S2.x); ROTPH(x1,x3,C2.y,S2.y);                            \
    ROTPH(x4,x6,C2.z,S2.z); ROTPH(x5,x7,C2.w,S2.w);                            \
    ROTPH(x0,x4,C3.x,S3.x); ROTPH(x1,x5,C3.y,S3.y);                            \
    ROTPH(x2,x6,C3.z,S3.z); ROTPH(x3,x7,C3.w,S3.w);                            \
  } while (0)

// ---- cs loads: one layer -> (uint4 c, uint4 s); table or sincos fallback ----
#define LCS1(CV, SV, LIDX) do { if (USE_TABLE) {                               \
    const char* _b = cs_tab + (size_t)(LIDX) * 2048 + (lane << 5);             \
    CV = *(const uint4*)_b; SV = *(const uint4*)(_b + 16);                     \
  } else {                                                                     \
    const float4* _p = (const float4*)(angles + (size_t)(LIDX)*512 + (lane<<3));\
    float4 _u = _p[0], _v = _p[1];                                             \
    float _c0,_c1,_c2,_c3,_c4,_c5,_c6,_c7,_t0,_t1,_t2,_t3,_t4,_t5,_t6,_t7;     \
    __sincosf(_u.x,&_t0,&_c0); __sincosf(_u.y,&_t1,&_c1);                      \
    __sincosf(_u.z,&_t2,&_c2); __sincosf(_u.w,&_t3,&_c3);                      \
    __sincosf(_v.x,&_t4,&_c4); __sincosf(_v.y,&_t5,&_c5);                      \
    __sincosf(_v.z,&_t6,&_c6); __sincosf(_v.w,&_t7,&_c7);                      \
    CV = make_uint4(PKU(_c0,_c1),PKU(_c2,_c3),PKU(_c4,_c5),PKU(_c6,_c7));      \
    SV = make_uint4(PKU(_t0,_t1),PKU(_t2,_t3),PKU(_t4,_t5),PKU(_t6,_t7));      \
  } } while (0)

#define LOAD_IN(M)  do { LCS1(cA0,sA0,(M)*8+0); LCS1(cA1,sA1,(M)*8+1);         \
                         LCS1(cA2,sA2,(M)*8+2); LCS1(cA3,sA3,(M)*8+3); } while (0)
#define LOAD_OUT(M) do { LCS1(cB0,sB0,(M)*8+4); LCS1(cB1,sB1,(M)*8+5);         \
                         LCS1(cB2,sB2,(M)*8+6); LCS1(cB3,sB3,(M)*8+7); } while (0)

// ---- addresses: 16 u16 byte-offsets packed into 2x int4 per module ----
#define A16(v)      (((v) << 1) + (((v) >> 5) << 2))
#define PK2(lo, hi) (int)((unsigned)A16(lo) | ((unsigned)A16(hi) << 16))
#define LOAD_ADDR(D0, D1, M) do { if (USE_TABLE) {                             \
    const int4* _ap = (const int4*)(addr_tab + (size_t)(M)*2048 + (lane << 5));\
    D0 = _ap[0]; D1 = _ap[1];                                                  \
  } else {                                                                     \
    const int4* _ip = (const int4*)(indices + (size_t)(M)*N_INW + (lane << 4));\
    int4 _v0=_ip[0], _v1=_ip[1], _v2=_ip[2], _v3=_ip[3];                       \
    D0.x = PK2(_v0.x,_v0.y); D0.y = PK2(_v0.z,_v0.w);                          \
    D0.z = PK2(_v1.x,_v1.y); D0.w = PK2(_v1.z,_v1.w);                          \
    D1.x = PK2(_v2.x,_v2.y); D1.y = PK2(_v2.z,_v2.w);                          \
    D1.z = PK2(_v3.x,_v3.y); D1.w = PK2(_v3.z,_v3.w);                          \
  } } while (0)

#define ALO(W) ((int)((unsigned)(W) & 0xffffu))
#define AHI(W) ((int)((unsigned)(W) >> 16))

// gather two u16 rows into one h2 register
#define GAT(R, W) do {                                                         \
    unsigned _lo = *(const unsigned short*)(L + ALO(W));                       \
    unsigned _hi = *(const unsigned short*)(L + AHI(W));                       \
    x##R = __builtin_bit_cast(h2, _lo | (_hi << 16)); } while (0)

// scatter one h2 register back to two u16 rows
#define SCAT(R, W) do {                                                        \
    unsigned _u = __builtin_bit_cast(unsigned, x##R);                          \
    *(unsigned short*)(L + ALO(W)) = (unsigned short)_u;                       \
    *(unsigned short*)(L + AHI(W)) = (unsigned short)(_u >> 16); } while (0)

// activation in fp32; two rows per register, fp32 bias per row
#define ACTH(X, B0, B1) do {                                                   \
    float _lo = (float)(X).x + (B0), _hi = (float)(X).y + (B1);                \
    _lo = 0.5f * (_lo + __builtin_amdgcn_sqrtf(_lo * _lo + 1.0f));             \
    _hi = 0.5f * (_hi + __builtin_amdgcn_sqrtf(_hi * _hi + 1.0f));             \
    X = __builtin_bit_cast(h2, PKU(_lo, _hi)); } while (0)

template <bool USE_TABLE>
__global__ __launch_bounds__(N_THREADS, 4)   // <=128 VGPR -> 4 waves/SIMD
void butterfly_fused_kernel(const float* __restrict__ input,
                            const float* __restrict__ scales,
                            const float* __restrict__ biases,
                            const int*   __restrict__ indices,
                            const char*  __restrict__ cs_tab,
                            const char*  __restrict__ addr_tab,
                            const float* __restrict__ angles,
                            float* __restrict__ out) {
    extern __shared__ float ldsbuf[];
    const int t    = threadIdx.x;
    const int lane = t & 63;         // butterfly block = lane
    const int w    = t >> 6;         // wave id; waves fully independent
    char* L = (char*)ldsbuf + w * SLAB_B;    // private per-wave slab
    const int b   = blockIdx.x;
    // XCD swizzle: blockIdx%8 == x owns columns [x*512,(x+1)*512)
    const int cg  = ((((b & 7) * 128) + (b >> 3)) << 2) + w;

    uint4 cA0,sA0,cA1,sA1,cA2,sA2,cA3,sA3;   // IN half-module cs (streaming)
    uint4 cB0,sB0,cB1,sB1,cB2,sB2,cB3,sB3;   // OUT half-module cs
    int4  ad0, ad1;                          // current module u16-packed addrs
    h2 x0, x1, x2, x3, x4, x5, x6, x7;

    // prologue: module 0 IN cs + addrs
    LOAD_IN(0);
    LOAD_ADDR(ad0, ad1, 0);

    // init: rows 0..1023 = scales[r] * input[r][cg], packed 2 rows / dword
#pragma unroll
    for (int k = 0; k < 8; ++k) {
        const int r = (k << 7) + (lane << 1);
        F2 sc = *(const F2*)(scales + r);
        float v0 = input[(size_t)r * N_BATCH + cg] * sc.x;
        float v1 = input[(size_t)(r + 1) * N_BATCH + cg] * sc.y;
        *(unsigned*)(L + ADDR(r)) = PKU(v0, v1);
    }

#pragma unroll 1
    for (int m = 0; m < 7; ++m) {
        int4 nad0, nad1;
        // step 1: issue OUT-cs + bias prefetch, then gather
        LOAD_OUT(m);
        const float4* _bp = (const float4*)(biases + (size_t)m * N_GROW + (lane << 3));
        float4 bb0 = _bp[0], bb1 = _bp[1];
        GAT(0, ad0.x); GAT(1, ad0.y); GAT(2, ad0.z); GAT(3, ad0.w);
        GAT(4, ad1.x); GAT(5, ad1.y); GAT(6, ad1.z); GAT(7, ad1.w);
        FENCE();
        // step 2: IN rotations + activation + act-row store
        ROT4(cA0,sA0,cA1,sA1,cA2,sA2,cA3,sA3);
        ACTH(x0, bb0.x, bb0.y); ACTH(x1, bb0.z, bb0.w);
        ACTH(x2, bb1.x, bb1.y); ACTH(x3, bb1.z, bb1.w);
        {
            const int _ab = ADDR(N_INW + m * N_GROW + (lane << 3));
            *(unsigned*)(L + _ab + 0)  = __builtin_bit_cast(unsigned, x0);
            *(unsigned*)(L + _ab + 4)  = __builtin_bit_cast(unsigned, x1);
            *(unsigned*)(L + _ab + 8)  = __builtin_bit_cast(unsigned, x2);
            *(unsigned*)(L + _ab + 12) = __builtin_bit_cast(unsigned, x3);
        }
        // step 3: prefetch next module IN-cs + addrs
        LOAD_IN(m + 1);
        LOAD_ADDR(nad0, nad1, m + 1);
        FENCE();
        // step 4: OUT rotations + scatter
        ROT4(cB0,sB0,cB1,sB1,cB2,sB2,cB3,sB3);
        SCAT(0, ad0.x); SCAT(1, ad0.y); SCAT(2, ad0.z); SCAT(3, ad0.w);
        SCAT(4, ad1.x); SCAT(5, ad1.y); SCAT(6, ad1.z); SCAT(7, ad1.w);
        ad0 = nad0; ad1 = nad1;
    }

    // epilogue: module 7 — OUT rotations + scatter are dead code;
    // output = module-7 activations (fp16 -> fp32).
    {
        const float4* _bp = (const float4*)(biases + (size_t)7 * N_GROW + (lane << 3));
        float4 bb0 = _bp[0], bb1 = _bp[1];
        GAT(0, ad0.x); GAT(1, ad0.y); GAT(2, ad0.z); GAT(3, ad0.w);
        GAT(4, ad1.x); GAT(5, ad1.y); GAT(6, ad1.z); GAT(7, ad1.w);
        FENCE();
        ROT4(cA0,sA0,cA1,sA1,cA2,sA2,cA3,sA3);
        ACTH(x0, bb0.x, bb0.y); ACTH(x1, bb0.z, bb0.w);
        ACTH(x2, bb1.x, bb1.y); ACTH(x3, bb1.z, bb1.w);
        float* op = out + (size_t)(lane << 3) * N_BATCH + cg;
        op[0 * N_BATCH] = (float)x0.x; op[1 * N_BATCH] = (float)x0.y;
        op[2 * N_BATCH] = (float)x1.x; op[3 * N_BATCH] = (float)x1.y;
        op[4 * N_BATCH] = (float)x2.x; op[5 * N_BATCH] = (float)x2.y;
        op[6 * N_BATCH] = (float)x3.x; op[7 * N_BATCH] = (float)x3.y;
    }
}

// ---------------- host ----------------
extern "C" void kernel_launch(void* const* d_in, const int* in_sizes, int n_in,
                              void* d_out, int out_size, void* d_ws, size_t ws_size,
                              hipStream_t stream) {
    const float* input   = (const float*)d_in[0];
    const float* scales  = (const float*)d_in[1];
    const float* angles  = (const float*)d_in[2];
    const float* biases  = (const float*)d_in[3];
    const int*   indices = (const int*)d_in[4];
    float* out = (float*)d_out;

    const size_t cs_bytes  = (size_t)N_LAYERS * 2048;                    // 128 KB fp16
    const size_t adr_bytes = (size_t)N_DEPTH * N_INW * 2;                // 16 KB u16
    const size_t lds_bytes = (size_t)4 * SLAB_B;                         // 39168 B
    const int grid = N_BATCH / 4;                                        // 1024 WGs

    if (ws_size >= cs_bytes + adr_bytes) {
        _Float16* csh = (_Float16*)d_ws;
        unsigned short* addrs = (unsigned short*)((char*)d_ws + cs_bytes);
        precompute_kernel<<<(N_LAYERS * 512 + 255) / 256, 256, 0, stream>>>(
            angles, indices, csh, addrs);
        butterfly_fused_kernel<true><<<grid, N_THREADS, lds_bytes, stream>>>(
            input, scales, biases, indices, (const char*)csh, (const char*)addrs,
            angles, out);
    } else {
        butterfly_fused_kernel<false><<<grid, N_THREADS, lds_bytes, stream>>>(
            input, scales, biases, indices, nullptr, nullptr, angles, out);
    }
}